// Round 6
// baseline (2894.744 us; speedup 1.0000x reference)
//
#include <hip/hip_runtime.h>

#define N_USERS 50000
#define N_ENT   150000
#define N_NODES 200000
#define NE      2000000
#define BATCH   8192
#define NCB     16          // col buckets per rowblock
#define CBSZ    12500       // cols per bucket (200000/16)
#define NKB     50000       // 3125 rowblocks * 16 colbuckets
#define NKBB    196         // ceil(NKB/256)

// ===========================================================================
// Bucketed edge sort: key = (row/64)*16 + col/12500.
// Blocks own 64 rows; walking edges in col-bucket order keeps the whole
// device inside a ~3.2MB col slice at a time -> gather hits L2/L3 instead of
// the 246MB/dispatch HBM misses measured in r4/r5.
// ===========================================================================
__global__ __launch_bounds__(256) void khist_kernel(const int* __restrict__ rows,
                                                    const int* __restrict__ cols,
                                                    int* __restrict__ hist) {
    int e = blockIdx.x * 256 + threadIdx.x;
    if (e < NE) {
        int k = (rows[e] >> 6) * NCB + cols[e] / CBSZ;
        atomicAdd(&hist[k], 1);
    }
}

__global__ __launch_bounds__(256) void kscan1(const int* __restrict__ hist,
                                              int* __restrict__ koff,
                                              int* __restrict__ blk) {
    __shared__ int buf[256];
    int i = blockIdx.x * 256 + threadIdx.x;
    int v = (i < NKB) ? hist[i] : 0;
    buf[threadIdx.x] = v;
    __syncthreads();
    for (int off = 1; off < 256; off <<= 1) {
        int x = (threadIdx.x >= off) ? buf[threadIdx.x - off] : 0;
        __syncthreads();
        buf[threadIdx.x] += x;
        __syncthreads();
    }
    if (i < NKB) koff[i] = buf[threadIdx.x] - v;        // exclusive
    if (threadIdx.x == 255) blk[blockIdx.x] = buf[255];
}

__global__ __launch_bounds__(1024) void kscan2(int* __restrict__ blk) {
    __shared__ int buf[1024];
    int t = threadIdx.x;
    int v = (t < NKBB) ? blk[t] : 0;
    buf[t] = v;
    __syncthreads();
    for (int off = 1; off < 1024; off <<= 1) {
        int x = (t >= off) ? buf[t - off] : 0;
        __syncthreads();
        buf[t] += x;
        __syncthreads();
    }
    if (t < NKBB) blk[t] = buf[t] - v;
}

__global__ __launch_bounds__(256) void kscan3(int* __restrict__ koff,
                                              const int* __restrict__ blk) {
    int i = blockIdx.x * 256 + threadIdx.x;
    if (i < NKB) koff[i] += blk[blockIdx.x];
}

__global__ __launch_bounds__(256) void kprep(const int* __restrict__ koff,
                                             int* __restrict__ kcur) {
    int i = blockIdx.x * 256 + threadIdx.x;
    if (i < NKB) kcur[i] = koff[i];
    if (i == 0) ((int*)koff)[NKB] = NE;   // sentinel end
}

__global__ __launch_bounds__(256) void kfill(const int* __restrict__ rows,
                                             const int* __restrict__ cols,
                                             const float* __restrict__ vals,
                                             int* __restrict__ kcur,
                                             int* __restrict__ ccol,
                                             float* __restrict__ cval,
                                             int* __restrict__ crow) {
    int e = blockIdx.x * 256 + threadIdx.x;
    if (e >= NE) return;
    int r = rows[e], c = cols[e];
    int k = (r >> 6) * NCB + c / CBSZ;
    int pos = atomicAdd(&kcur[k], 1);
    ccol[pos] = c;
    cval[pos] = vals[e];
    crow[pos] = r;
}

// ===========================================================================
// Edge-parallel gather: block owns rows [r0, r0+64); its edges are contiguous
// [koff[b*16], koff[b*16+16]) and ordered by col bucket. DIN/4 lanes per edge
// (float4), 8 edges staged -> 8 float4 loads in flight before any LDS atomic.
// LDS f32 atomics into padded side tile; rows block-owned -> no global atomics.
// ===========================================================================
template <int DIN, int L0>
__global__ __launch_bounds__(256) void gather_kernel(
        const int* __restrict__ koff,
        const int* __restrict__ ccol, const float* __restrict__ cval,
        const int* __restrict__ crow,
        const float* __restrict__ ue, const float* __restrict__ ee,
        const float* __restrict__ xin, float* __restrict__ side_g) {
    constexpr int LPE = DIN / 4;       // lanes per edge (16 or 8)
    constexpr int GROUPS = 256 / LPE;  // edges per block round (16 or 32)
    constexpr int U = 8;               // edges staged per group
    constexpr int PAD = DIN + 1;
    __shared__ float ss[64 * PAD];
    const int tid = threadIdx.x;
    for (int i = tid; i < 64 * PAD; i += 256) ss[i] = 0.f;
    const int r0     = blockIdx.x * 64;
    const int estart = koff[blockIdx.x * NCB];
    const int eend   = koff[blockIdx.x * NCB + NCB];
    const int group  = tid / LPE;
    const int sub    = tid % LPE;
    __syncthreads();

    for (int eb = estart; eb < eend; eb += GROUPS * U) {
        int   col[U], lr[U];
        float v[U];
        bool  ok[U];
#pragma unroll
        for (int u = 0; u < U; u++) {
            int e = eb + u * GROUPS + group;
            ok[u]  = (e < eend);
            col[u] = ok[u] ? ccol[e] : 0;
            v[u]   = ok[u] ? cval[e] : 0.f;
            lr[u]  = ok[u] ? (crow[e] - r0) : 0;
        }
        float4 x[U];
#pragma unroll
        for (int u = 0; u < U; u++) {
            if (L0) {
                const float* base = (col[u] < N_USERS)
                    ? (ue + (size_t)col[u] * 64)
                    : (ee + (size_t)(col[u] - N_USERS) * 64);
                x[u] = ((const float4*)base)[sub];
            } else {
                x[u] = ((const float4*)(xin + (size_t)col[u] * DIN))[sub];
            }
        }
#pragma unroll
        for (int u = 0; u < U; u++) {
            if (ok[u]) {
                float* d = &ss[lr[u] * PAD + sub * 4];
                __hip_atomic_fetch_add(d + 0, v[u] * x[u].x, __ATOMIC_RELAXED, __HIP_MEMORY_SCOPE_WORKGROUP);
                __hip_atomic_fetch_add(d + 1, v[u] * x[u].y, __ATOMIC_RELAXED, __HIP_MEMORY_SCOPE_WORKGROUP);
                __hip_atomic_fetch_add(d + 2, v[u] * x[u].z, __ATOMIC_RELAXED, __HIP_MEMORY_SCOPE_WORKGROUP);
                __hip_atomic_fetch_add(d + 3, v[u] * x[u].w, __ATOMIC_RELAXED, __HIP_MEMORY_SCOPE_WORKGROUP);
            }
        }
    }
    __syncthreads();
    for (int i = tid; i < 64 * DIN; i += 256) {
        int r = i / DIN, d = i % DIN;
        side_g[(size_t)(r0 + r) * DIN + d] = ss[r * PAD + d];
    }
}

// ===========================================================================
// Transform: R = 64/DOUT rows per wave; block = 1024 (weight-LDS amortized).
// Shuffle-both-registers-then-select (verified). Writes UNNORMALIZED xout
// (stride DOUT) + row norm; normalization folded into scoring.
// ===========================================================================
template <int DIN, int DOUT, int L0>
__global__ __launch_bounds__(1024) void transform_kernel(
        const float* __restrict__ ue, const float* __restrict__ ee,
        const float* __restrict__ xin,   // stride DIN (ignored if L0)
        const float* __restrict__ side,  // stride DIN
        const float* __restrict__ Wg, const float* __restrict__ bg,
        const float* __restrict__ Wb, const float* __restrict__ bb,
        float* __restrict__ xout,        // stride DOUT, unnormalized
        float* __restrict__ norm_out) {
    __shared__ float sWg[DIN * DOUT];
    __shared__ float sWb[DIN * DOUT];
    __shared__ float sbg[DOUT];
    __shared__ float sbb[DOUT];
    for (int i = threadIdx.x; i < DIN * DOUT; i += 1024) {
        sWg[i] = Wg[i];
        sWb[i] = Wb[i];
    }
    if (threadIdx.x < DOUT) {
        sbg[threadIdx.x] = bg[threadIdx.x];
        sbb[threadIdx.x] = bb[threadIdx.x];
    }
    __syncthreads();

    constexpr int R     = 64 / DOUT;
    constexpr int NSLOT = R * DIN;
    constexpr int REGS  = (NSLOT + 63) / 64;

    const int lane  = threadIdx.x & 63;
    const int wave  = threadIdx.x >> 6;
    const int sub   = lane / DOUT;
    const int j     = lane % DOUT;
    const int wrow0 = blockIdx.x * (16 * R) + wave * R;

    float hreg[REGS], preg[REGS];
#pragma unroll
    for (int t = 0; t < REGS; t++) {
        int slot = lane + t * 64;
        int r = slot / DIN, k = slot % DIN;
        int row = wrow0 + r;
        float e;
        if (L0) {
            e = (row < N_USERS) ? ue[(size_t)row * 64 + k]
                                : ee[(size_t)(row - N_USERS) * 64 + k];
        } else {
            e = xin[(size_t)row * DIN + k];
        }
        float s = side[(size_t)row * DIN + k];
        hreg[t] = e + s;
        preg[t] = e * s;
    }

    float ag = sbg[j];
    float ab = sbb[j];
#pragma unroll
    for (int k = 0; k < DIN; k++) {
        const int slot = sub * DIN + k;
        const int src  = slot & 63;
        float hk, pk;
        if (REGS > 1) {
            float h0 = __shfl(hreg[0], src);
            float p0 = __shfl(preg[0], src);
            float h1 = __shfl(hreg[REGS - 1], src);
            float p1 = __shfl(preg[REGS - 1], src);
            int rsel = slot >> 6;
            hk = rsel ? h1 : h0;
            pk = rsel ? p1 : p0;
        } else {
            hk = __shfl(hreg[0], src);
            pk = __shfl(preg[0], src);
        }
        ag = fmaf(hk, sWg[k * DOUT + j], ag);
        ab = fmaf(pk, sWb[k * DOUT + j], ab);
    }
    ag = ag > 0.f ? ag : 0.01f * ag;   // leaky_relu slope 0.01
    ab = ab > 0.f ? ab : 0.01f * ab;
    float nv = ag + ab;

    float ss = nv * nv;
#pragma unroll
    for (int off = DOUT / 2; off > 0; off >>= 1) ss += __shfl_xor(ss, off);
    float nrm = fmaxf(sqrtf(ss), 1e-12f);

    const int row = wrow0 + sub;
    xout[(size_t)row * DOUT + j] = nv;
    if (j == 0) norm_out[row] = nrm;
}

// ===========================================================================
// Scoring: one wave per batch element; sections 64 raw + 64/n0 + 32/n1 + 16/n2.
// ===========================================================================
__global__ __launch_bounds__(256) void score_kernel(
        const int* __restrict__ users, const int* __restrict__ pos,
        const int* __restrict__ neg,
        const float* __restrict__ ue, const float* __restrict__ ee,
        const float* __restrict__ e1, const float* __restrict__ n0,
        const float* __restrict__ e2, const float* __restrict__ n1,
        const float* __restrict__ e3, const float* __restrict__ n2,
        float* __restrict__ out) {
    int gid  = blockIdx.x * 256 + threadIdx.x;
    int idx  = gid >> 6;
    int lane = gid & 63;
    if (idx >= BATCH) return;
    int u  = users[idx];
    int pe = pos[idx];
    int ne = neg[idx];
    int pn = N_USERS + pe;
    int nn = N_USERS + ne;

    float s1p = 1.0f / (n0[u] * n0[pn]);
    float s1n = 1.0f / (n0[u] * n0[nn]);
    float s2p = 1.0f / (n1[u] * n1[pn]);
    float s2n = 1.0f / (n1[u] * n1[nn]);
    float s3p = 1.0f / (n2[u] * n2[pn]);
    float s3n = 1.0f / (n2[u] * n2[nn]);

    float ap = 0.f, an = 0.f;
    {
        float xu = ue[(size_t)u * 64 + lane];
        ap += xu * ee[(size_t)pe * 64 + lane];
        an += xu * ee[(size_t)ne * 64 + lane];
    }
    {
        float xu = e1[(size_t)u * 64 + lane];
        ap += xu * e1[(size_t)pn * 64 + lane] * s1p;
        an += xu * e1[(size_t)nn * 64 + lane] * s1n;
    }
    if (lane < 32) {
        float xu = e2[(size_t)u * 32 + lane];
        ap += xu * e2[(size_t)pn * 32 + lane] * s2p;
        an += xu * e2[(size_t)nn * 32 + lane] * s2n;
    } else if (lane < 48) {
        int d = lane - 32;
        float xu = e3[(size_t)u * 16 + d];
        ap += xu * e3[(size_t)pn * 16 + d] * s3p;
        an += xu * e3[(size_t)nn * 16 + d] * s3n;
    }
#pragma unroll
    for (int off = 32; off > 0; off >>= 1) {
        ap += __shfl_xor(ap, off);
        an += __shfl_xor(an, off);
    }
    if (lane == 0) {
        out[2 * idx + 0] = ap;
        out[2 * idx + 1] = an;
    }
}

// ===========================================================================
extern "C" void kernel_launch(void* const* d_in, const int* in_sizes, int n_in,
                              void* d_out, int out_size, void* d_ws, size_t ws_size,
                              hipStream_t stream) {
    const int*   users = (const int*)d_in[0];
    const int*   pos   = (const int*)d_in[1];
    const int*   neg   = (const int*)d_in[2];
    const int*   rows  = (const int*)d_in[3];
    const int*   cols  = (const int*)d_in[4];
    const float* vals  = (const float*)d_in[5];
    const float* ue    = (const float*)d_in[6];
    const float* ee    = (const float*)d_in[7];
    const float* Wg0 = (const float*)d_in[8],  *bg0 = (const float*)d_in[9];
    const float* Wb0 = (const float*)d_in[10], *bb0 = (const float*)d_in[11];
    const float* Wg1 = (const float*)d_in[12], *bg1 = (const float*)d_in[13];
    const float* Wb1 = (const float*)d_in[14], *bb1 = (const float*)d_in[15];
    const float* Wg2 = (const float*)d_in[16], *bg2 = (const float*)d_in[17];
    const float* Wb2 = (const float*)d_in[18], *bb2 = (const float*)d_in[19];

    // workspace (~168 MB; 192 MB proven available in round 2)
    float* e1   = (float*)d_ws;                      // N x 64 (unnormalized)
    float* e2   = e1   + (size_t)N_NODES * 64;       // N x 32
    float* e3   = e2   + (size_t)N_NODES * 32;       // N x 16
    float* n0   = e3   + (size_t)N_NODES * 16;       // N
    float* n1   = n0   + N_NODES;                    // N
    float* n2   = n1   + N_NODES;                    // N
    float* side = n2   + N_NODES;                    // N x 64 scratch
    float* cval = side + (size_t)N_NODES * 64;       // E
    int*   ccol = (int*)(cval + NE);                 // E
    int*   crow = ccol + NE;                         // E
    int*   koff = crow + NE;                         // NKB+1
    int*   kcur = koff + NKB + 1;                    // NKB (also histogram)
    int*   blk  = kcur + NKB;                        // NKBB scratch

    // ---- bucketed edge sort (once, reused by all 3 layers) ----
    hipMemsetAsync(kcur, 0, NKB * sizeof(int), stream);
    khist_kernel<<<(NE + 255) / 256, 256, 0, stream>>>(rows, cols, kcur);
    kscan1<<<NKBB, 256, 0, stream>>>(kcur, koff, blk);
    kscan2<<<1, 1024, 0, stream>>>(blk);
    kscan3<<<NKBB, 256, 0, stream>>>(koff, blk);
    kprep<<<NKBB, 256, 0, stream>>>(koff, kcur);
    kfill<<<(NE + 255) / 256, 256, 0, stream>>>(rows, cols, vals, kcur, ccol, cval, crow);

    // ---- layer 0 ----
    gather_kernel<64, 1><<<3125, 256, 0, stream>>>(koff, ccol, cval, crow,
                                                   ue, ee, nullptr, side);
    transform_kernel<64, 64, 1><<<12500, 1024, 0, stream>>>(ue, ee, nullptr, side,
                                                            Wg0, bg0, Wb0, bb0, e1, n0);
    // ---- layer 1 ----
    gather_kernel<64, 0><<<3125, 256, 0, stream>>>(koff, ccol, cval, crow,
                                                   ue, ee, e1, side);
    transform_kernel<64, 32, 0><<<6250, 1024, 0, stream>>>(ue, ee, e1, side,
                                                           Wg1, bg1, Wb1, bb1, e2, n1);
    // ---- layer 2 ----
    gather_kernel<32, 0><<<3125, 256, 0, stream>>>(koff, ccol, cval, crow,
                                                   ue, ee, e2, side);
    transform_kernel<32, 16, 0><<<3125, 1024, 0, stream>>>(ue, ee, e2, side,
                                                           Wg2, bg2, Wb2, bb2, e3, n2);

    // ---- scoring ----
    score_kernel<<<(BATCH * 64) / 256, 256, 0, stream>>>(users, pos, neg, ue, ee,
                                                         e1, n0, e2, n1, e3, n2,
                                                         (float*)d_out);
}

// Round 7
// 1417.067 us; speedup vs baseline: 2.0428x; 2.0428x over previous
//
#include <hip/hip_runtime.h>

#define N_USERS 50000
#define N_ENT   150000
#define N_NODES 200000
#define NE      2000000
#define BATCH   8192
#define NB 782          // ceil(N_NODES / 256)

__device__ __forceinline__ float bf2f(unsigned short b) {
    return __uint_as_float(((unsigned int)b) << 16);
}
__device__ __forceinline__ unsigned short f2bf(float f) {
    unsigned int u = __float_as_uint(f);
    u += 0x7FFF + ((u >> 16) & 1);          // round-to-nearest-even
    return (unsigned short)(u >> 16);
}

// ===========================================================================
// CSR build: histogram -> exclusive scan -> atomic-cursor fill.
// After fill, rs[r] == row_end; row_start = rs[r] - deg[r].
// ===========================================================================
__global__ __launch_bounds__(256) void hist_kernel(const int* __restrict__ rows,
                                                   int* __restrict__ deg) {
    int e = blockIdx.x * 256 + threadIdx.x;
    if (e < NE) atomicAdd(&deg[rows[e]], 1);
}

__global__ __launch_bounds__(256) void scan1(const int* __restrict__ deg,
                                             int* __restrict__ rs,
                                             int* __restrict__ blk) {
    __shared__ int buf[256];
    int i = blockIdx.x * 256 + threadIdx.x;
    int v = (i < N_NODES) ? deg[i] : 0;
    buf[threadIdx.x] = v;
    __syncthreads();
    for (int off = 1; off < 256; off <<= 1) {
        int x = (threadIdx.x >= off) ? buf[threadIdx.x - off] : 0;
        __syncthreads();
        buf[threadIdx.x] += x;
        __syncthreads();
    }
    if (i < N_NODES) rs[i] = buf[threadIdx.x] - v;       // exclusive
    if (threadIdx.x == 255) blk[blockIdx.x] = buf[255];
}

__global__ __launch_bounds__(1024) void scan2(int* __restrict__ blk) {
    __shared__ int buf[1024];
    int t = threadIdx.x;
    int v = (t < NB) ? blk[t] : 0;
    buf[t] = v;
    __syncthreads();
    for (int off = 1; off < 1024; off <<= 1) {
        int x = (t >= off) ? buf[t - off] : 0;
        __syncthreads();
        buf[t] += x;
        __syncthreads();
    }
    if (t < NB) blk[t] = buf[t] - v;
}

__global__ __launch_bounds__(256) void scan3(int* __restrict__ rs,
                                             const int* __restrict__ blk) {
    int i = blockIdx.x * 256 + threadIdx.x;
    if (i < N_NODES) rs[i] += blk[blockIdx.x];
}

__global__ __launch_bounds__(256) void fill_kernel(const int* __restrict__ rows,
                                                   const int* __restrict__ cols,
                                                   const float* __restrict__ vals,
                                                   int* __restrict__ rs,
                                                   int* __restrict__ ccol,
                                                   float* __restrict__ cval) {
    int e = blockIdx.x * 256 + threadIdx.x;
    if (e >= NE) return;
    int pos = atomicAdd(&rs[rows[e]], 1);
    ccol[pos] = cols[e];
    cval[pos] = vals[e];
}

// ---------------------------------------------------------------------------
// t0 = bf16(concat(ue, ee)) — the layer-0 gather table. One 64-dim row is
// 128 B = ONE cache line (fp32 was 2) -> halves random-miss bytes AND lines.
// ---------------------------------------------------------------------------
__global__ __launch_bounds__(256) void build_t0(const float* __restrict__ ue,
                                                const float* __restrict__ ee,
                                                unsigned short* __restrict__ t0) {
    int i = blockIdx.x * 256 + threadIdx.x;              // float4 index
    const int total = N_NODES * 64 / 4;
    if (i >= total) return;
    const int uelems = N_USERS * 64 / 4;
    float4 v = (i < uelems) ? ((const float4*)ue)[i]
                            : ((const float4*)ee)[i - uelems];
    ushort4 o;
    o.x = f2bf(v.x); o.y = f2bf(v.y); o.z = f2bf(v.z); o.w = f2bf(v.w);
    ((ushort4*)t0)[i] = o;
}

// ===========================================================================
// Fused per-layer kernel (r4 structure — measured best): one wave per row
// (DIN=64) or 2 edge-slots/wave (DIN=32). Gather reads the bf16 table tin
// (unnormalized previous-layer output; reference feeds unnormalized ego
// forward). Own ego read fp32. 4-edge ILP, zero-padded batches.
// Epilogue: xout fp32 (own-ego/scoring), tout bf16 (next gather), norm.
// Block=1024 so weight-LDS is amortized (r3->r4 occupancy fix).
// ===========================================================================
template <int DIN, int DOUT, int L0, int WT>
__global__ __launch_bounds__(1024) void spmm_transform(
        const int* __restrict__ rs, const int* __restrict__ deg,
        const int* __restrict__ ccol, const float* __restrict__ cval,
        const unsigned short* __restrict__ tin,
        const float* __restrict__ ue, const float* __restrict__ ee,
        const float* __restrict__ xin,            // fp32 prev layer (stride DIN)
        const float* __restrict__ Wg, const float* __restrict__ bg,
        const float* __restrict__ Wb, const float* __restrict__ bb,
        float* __restrict__ xout,                 // fp32, stride DOUT
        unsigned short* __restrict__ tout,        // bf16, stride DOUT (if WT)
        float* __restrict__ norm_out) {
    __shared__ float sWg[DIN * DOUT];
    __shared__ float sWb[DIN * DOUT];
    __shared__ float sbg[DOUT];
    __shared__ float sbb[DOUT];
    for (int i = threadIdx.x; i < DIN * DOUT; i += 1024) {
        sWg[i] = Wg[i];
        sWb[i] = Wb[i];
    }
    if (threadIdx.x < DOUT) {
        sbg[threadIdx.x] = bg[threadIdx.x];
        sbb[threadIdx.x] = bb[threadIdx.x];
    }
    __syncthreads();

    constexpr int EPG = 64 / DIN;     // edge slots per wave iteration
    const int lane = threadIdx.x & 63;
    const int g    = lane / DIN;      // edge sub-slot (0 for DIN=64)
    const int d    = lane % DIN;      // dim
    const int row  = (blockIdx.x * 1024 + threadIdx.x) >> 6;  // grid exact

    // ---- CSR gather with 4-way ILP (bf16 table) ----
    float acc0 = 0.f, acc1 = 0.f, acc2 = 0.f, acc3 = 0.f;
    const int end   = rs[row];
    const int start = end - deg[row];
    for (int base = start; base < end; base += 64) {
        int n = end - base;
        if (n > 64) n = 64;
        int   mycol = 0;
        float myval = 0.f;                 // 0 for pad lanes -> fma adds 0
        if (lane < n) {
            mycol = ccol[base + lane];
            myval = cval[base + lane];
        }
        const int np = (n + 4 * EPG - 1) & ~(4 * EPG - 1);  // pad to unroll width
        for (int i = 0; i < np; i += 4 * EPG) {
            int c0 = __shfl(mycol, i + 0 * EPG + g);
            int c1 = __shfl(mycol, i + 1 * EPG + g);
            int c2 = __shfl(mycol, i + 2 * EPG + g);
            int c3 = __shfl(mycol, i + 3 * EPG + g);
            float v0 = __shfl(myval, i + 0 * EPG + g);
            float v1 = __shfl(myval, i + 1 * EPG + g);
            float v2 = __shfl(myval, i + 2 * EPG + g);
            float v3 = __shfl(myval, i + 3 * EPG + g);
            float x0 = bf2f(tin[(size_t)c0 * DIN + d]);
            float x1 = bf2f(tin[(size_t)c1 * DIN + d]);
            float x2 = bf2f(tin[(size_t)c2 * DIN + d]);
            float x3 = bf2f(tin[(size_t)c3 * DIN + d]);
            acc0 = fmaf(v0, x0, acc0);
            acc1 = fmaf(v1, x1, acc1);
            acc2 = fmaf(v2, x2, acc2);
            acc3 = fmaf(v3, x3, acc3);
        }
    }
    float acc = (acc0 + acc1) + (acc2 + acc3);
    if (DIN == 32) acc += __shfl_xor(acc, 32);   // combine the 2 edge sub-slots

    // ---- own ego value (fp32) ----
    float e = 0.f;
    if (lane < DIN) {
        if (L0) {
            e = (row < N_USERS) ? ue[(size_t)row * 64 + lane]
                                : ee[(size_t)(row - N_USERS) * 64 + lane];
        } else {
            e = xin[(size_t)row * DIN + lane];
        }
    }
    float h = e + acc;
    float p = e * acc;

    // ---- dense transform via wave broadcast ----
    float ag = (lane < DOUT) ? sbg[lane] : 0.f;
    float ab = (lane < DOUT) ? sbb[lane] : 0.f;
#pragma unroll
    for (int k = 0; k < DIN; k++) {
        float hk = __shfl(h, k);
        float pk = __shfl(p, k);
        if (lane < DOUT) {
            ag = fmaf(hk, sWg[k * DOUT + lane], ag);
            ab = fmaf(pk, sWb[k * DOUT + lane], ab);
        }
    }
    ag = ag > 0.f ? ag : 0.01f * ag;   // leaky_relu slope 0.01
    ab = ab > 0.f ? ab : 0.01f * ab;
    float nv = (lane < DOUT) ? (ag + ab) : 0.f;

    float ss = nv * nv;
#pragma unroll
    for (int off = 32; off > 0; off >>= 1) ss += __shfl_xor(ss, off);
    float nrm = fmaxf(sqrtf(ss), 1e-12f);

    if (lane < DOUT) {
        xout[(size_t)row * DOUT + lane] = nv;
        if (WT) tout[(size_t)row * DOUT + lane] = f2bf(nv);
    }
    if (lane == 0) norm_out[row] = nrm;
}

// ===========================================================================
// Scoring: one wave per batch element; sections 64 raw + 64/n0 + 32/n1 + 16/n2
// (normalization folded in as division by the norm product — r5-verified).
// ===========================================================================
__global__ __launch_bounds__(256) void score_kernel(
        const int* __restrict__ users, const int* __restrict__ pos,
        const int* __restrict__ neg,
        const float* __restrict__ ue, const float* __restrict__ ee,
        const float* __restrict__ e1, const float* __restrict__ n0,
        const float* __restrict__ e2, const float* __restrict__ n1,
        const float* __restrict__ e3, const float* __restrict__ n2,
        float* __restrict__ out) {
    int gid  = blockIdx.x * 256 + threadIdx.x;
    int idx  = gid >> 6;
    int lane = gid & 63;
    if (idx >= BATCH) return;
    int u  = users[idx];
    int pe = pos[idx];
    int ne = neg[idx];
    int pn = N_USERS + pe;
    int nn = N_USERS + ne;

    float s1p = 1.0f / (n0[u] * n0[pn]);
    float s1n = 1.0f / (n0[u] * n0[nn]);
    float s2p = 1.0f / (n1[u] * n1[pn]);
    float s2n = 1.0f / (n1[u] * n1[nn]);
    float s3p = 1.0f / (n2[u] * n2[pn]);
    float s3n = 1.0f / (n2[u] * n2[nn]);

    float ap = 0.f, an = 0.f;
    {
        float xu = ue[(size_t)u * 64 + lane];
        ap += xu * ee[(size_t)pe * 64 + lane];
        an += xu * ee[(size_t)ne * 64 + lane];
    }
    {
        float xu = e1[(size_t)u * 64 + lane];
        ap += xu * e1[(size_t)pn * 64 + lane] * s1p;
        an += xu * e1[(size_t)nn * 64 + lane] * s1n;
    }
    if (lane < 32) {
        float xu = e2[(size_t)u * 32 + lane];
        ap += xu * e2[(size_t)pn * 32 + lane] * s2p;
        an += xu * e2[(size_t)nn * 32 + lane] * s2n;
    } else if (lane < 48) {
        int d = lane - 32;
        float xu = e3[(size_t)u * 16 + d];
        ap += xu * e3[(size_t)pn * 16 + d] * s3p;
        an += xu * e3[(size_t)nn * 16 + d] * s3n;
    }
#pragma unroll
    for (int off = 32; off > 0; off >>= 1) {
        ap += __shfl_xor(ap, off);
        an += __shfl_xor(an, off);
    }
    if (lane == 0) {
        out[2 * idx + 0] = ap;
        out[2 * idx + 1] = an;
    }
}

// ===========================================================================
extern "C" void kernel_launch(void* const* d_in, const int* in_sizes, int n_in,
                              void* d_out, int out_size, void* d_ws, size_t ws_size,
                              hipStream_t stream) {
    const int*   users = (const int*)d_in[0];
    const int*   pos   = (const int*)d_in[1];
    const int*   neg   = (const int*)d_in[2];
    const int*   rows  = (const int*)d_in[3];
    const int*   cols  = (const int*)d_in[4];
    const float* vals  = (const float*)d_in[5];
    const float* ue    = (const float*)d_in[6];
    const float* ee    = (const float*)d_in[7];
    const float* Wg0 = (const float*)d_in[8],  *bg0 = (const float*)d_in[9];
    const float* Wb0 = (const float*)d_in[10], *bb0 = (const float*)d_in[11];
    const float* Wg1 = (const float*)d_in[12], *bg1 = (const float*)d_in[13];
    const float* Wb1 = (const float*)d_in[14], *bb1 = (const float*)d_in[15];
    const float* Wg2 = (const float*)d_in[16], *bg2 = (const float*)d_in[17];
    const float* Wb2 = (const float*)d_in[18], *bb2 = (const float*)d_in[19];

    // workspace (~174 MB; >=192 MB proven available in round 2)
    float* e1 = (float*)d_ws;                            // N x 64 fp32 (unnorm)
    float* e2 = e1 + (size_t)N_NODES * 64;               // N x 32
    float* e3 = e2 + (size_t)N_NODES * 32;               // N x 16
    float* n0 = e3 + (size_t)N_NODES * 16;               // N
    float* n1 = n0 + N_NODES;                            // N
    float* n2 = n1 + N_NODES;                            // N
    float* cval = n2 + N_NODES;                          // E
    unsigned short* t0 = (unsigned short*)(cval + NE);   // N x 64 bf16
    unsigned short* t1 = t0 + (size_t)N_NODES * 64;      // N x 64 bf16
    unsigned short* t2 = t1 + (size_t)N_NODES * 64;      // N x 32 bf16
    int* ccol = (int*)(t2 + (size_t)N_NODES * 32);       // E
    int* deg  = ccol + NE;                               // N
    int* rs   = deg + N_NODES;                           // N
    int* blk  = rs + N_NODES;                            // 1024

    // ---- CSR build + bf16 layer-0 table (once) ----
    hipMemsetAsync(deg, 0, N_NODES * sizeof(int), stream);
    hist_kernel<<<(NE + 255) / 256, 256, 0, stream>>>(rows, deg);
    scan1<<<NB, 256, 0, stream>>>(deg, rs, blk);
    scan2<<<1, 1024, 0, stream>>>(blk);
    scan3<<<NB, 256, 0, stream>>>(rs, blk);
    fill_kernel<<<(NE + 255) / 256, 256, 0, stream>>>(rows, cols, vals, rs, ccol, cval);
    build_t0<<<(N_NODES * 64 / 4 + 255) / 256, 256, 0, stream>>>(ue, ee, t0);

    // ---- 3 fused layers: wave per row, block=1024, bf16 gather tables ----
    const int grid = N_NODES * 64 / 1024;  // 12500, exact
    spmm_transform<64, 64, 1, 1><<<grid, 1024, 0, stream>>>(
        rs, deg, ccol, cval, t0, ue, ee, nullptr,
        Wg0, bg0, Wb0, bb0, e1, t1, n0);
    spmm_transform<64, 32, 0, 1><<<grid, 1024, 0, stream>>>(
        rs, deg, ccol, cval, t1, ue, ee, e1,
        Wg1, bg1, Wb1, bb1, e2, t2, n1);
    spmm_transform<32, 16, 0, 0><<<grid, 1024, 0, stream>>>(
        rs, deg, ccol, cval, t2, ue, ee, e2,
        Wg2, bg2, Wb2, bb2, e3, nullptr, n2);

    // ---- scoring ----
    score_kernel<<<(BATCH * 64) / 256, 256, 0, stream>>>(users, pos, neg, ue, ee,
                                                         e1, n0, e2, n1, e3, n2,
                                                         (float*)d_out);
}